// Round 14
// baseline (417.637 us; speedup 1.0000x reference)
//
#include <hip/hip_runtime.h>

// GCN 2-layer forward, CSR-gather formulation. All fp32.
// out[d] = dinv[d] * ( sum_{e: src->d} g[src] + g[d] ) + bias,
// where g[i] = (h W)[i] * dinv[i]; self-loop is the +g[d] term.
// CSR built via SINGLE-PASS capacity binning (each dst-bucket owns a fixed
// CAP-slot region; uniform-random dst -> max bucket load ~8200 << CAP=10240):
//   k_bin:    stage edges in regs, LDS hist+scan, one global reserve per
//             (block,bucket) from zero-seeded cursor, LDS counting sort,
//             COALESCED write of packed (src<<8|dst&255) runs into b*CAP+...
//   k_place:  per-bucket (512 thr): per-node counts/scan in LDS, emit
//             row_start (capacity-absolute), cnt, dinv; place csr.
//   k_gemm1:  g1 = (x @ W1) * dinv. W1 in LDS (o-major XOR-swizzled);
//             4 rows/wave/iter; launch_bounds(256,4) caps VGPR at 128 ->
//             4 blocks/CU (128KB LDS) x 4 waves = 16 waves/CU to hide HBM
//             latency (r13's (256,2) gave only 8 waves/CU).
//   k_gather1: CSR gather of g1 (4-way MLP unroll) + fused relu/W2 -> g2
//   k_gather2: CSR gather of g2 + bias -> out

#define BKT_SHIFT 8            // 256 nodes per bucket
#define BIN_EPT 16             // edges per thread in k_bin (4096/block)
#define CAP 10240              // per-bucket capacity (expected 8184, sigma~90)

// Bin packed edges (src<<8 | dst&255) into per-bucket capacity regions.
// LDS counting sort inside the block -> coalesced run writes.
// Dynamic LDS: h[NB], ls[NB], gb[NB], sorted[4096] int, bkt[4096] ushort.
__global__ __launch_bounds__(256) void k_bin(
    const int* __restrict__ src, const int* __restrict__ dst,
    int* __restrict__ bucket_cursor, int* __restrict__ binned, int E, int NB) {
    extern __shared__ int lds[];
    int* h  = lds;
    int* ls = lds + NB;
    int* gb = lds + 2 * NB;
    int* sorted = lds + 3 * NB;
    unsigned short* bkt = (unsigned short*)(sorted + 256 * BIN_EPT);
    const int t = threadIdx.x;
    const int base = blockIdx.x * (256 * BIN_EPT);
    const int count = min(256 * BIN_EPT, E - base);  // valid edges this block

    for (int b = t; b < NB; b += 256) h[b] = 0;
    __syncthreads();
    // Stage edges in registers + local histogram.
    int s_[BIN_EPT], d_[BIN_EPT];
#pragma unroll
    for (int j = 0; j < BIN_EPT; ++j) {
        int e = base + j * 256 + t;
        if (e < E) {
            s_[j] = src[e];
            d_[j] = dst[e];
            atomicAdd(&h[d_[j] >> BKT_SHIFT], 1);
        }
    }
    __syncthreads();
    // Inclusive Hillis-Steele scan of h into ls (512 padded slots, 2/thread).
    {
        int i0 = t, i1 = t + 256;
        ls[i0] = (i0 < NB) ? h[i0] : 0;
        ls[i1] = (i1 < NB) ? h[i1] : 0;
        __syncthreads();
        for (int off = 1; off < 512; off <<= 1) {
            int a0 = (i0 >= off) ? ls[i0 - off] : 0;
            int a1 = (i1 >= off) ? ls[i1 - off] : 0;
            __syncthreads();
            ls[i0] += a0; ls[i1] += a1;
            __syncthreads();
        }
    }
    // ls -> exclusive; reserve capacity-region space; h becomes sort cursor.
    for (int b = t; b < NB; b += 256) {
        int c = h[b];
        int ex = ls[b] - c;
        ls[b] = ex;
        gb[b] = (c > 0) ? (b * CAP + atomicAdd(&bucket_cursor[b], c)) : 0;
        h[b] = ex;
    }
    __syncthreads();
    // Counting sort into LDS.
#pragma unroll
    for (int j = 0; j < BIN_EPT; ++j) {
        int e = base + j * 256 + t;
        if (e < E) {
            int b = d_[j] >> BKT_SHIFT;
            int r = atomicAdd(&h[b], 1);
            sorted[r] = (s_[j] << BKT_SHIFT) | (d_[j] & 255);
            bkt[r] = (unsigned short)b;
        }
    }
    __syncthreads();
    // Coalesced write-out: consecutive slots -> consecutive positions in the
    // same bucket's reserved run.
#pragma unroll
    for (int j = 0; j < BIN_EPT; ++j) {
        int i = j * 256 + t;
        if (i < count) {
            int b = bkt[i];
            binned[gb[b] + (i - ls[b])] = sorted[i];
        }
    }
}

// One block (512 thr) per bucket: per-node degree count in LDS (4x staged),
// LDS scan -> row_start (capacity-absolute) + cnt + dinv, place csr.
__global__ __launch_bounds__(512) void k_place(
    const int* __restrict__ binned, const int* __restrict__ bucket_cursor,
    int* __restrict__ row_start, int* __restrict__ cnt, float* __restrict__ dinv,
    int* __restrict__ csr, int n, int NB) {
    __shared__ int lcnt[256], sc[256];
    const int b = blockIdx.x;
    const int t = threadIdx.x;
    const int lo = b * CAP;
    const int hi = lo + bucket_cursor[b];  // final cursor == bucket count
    if (t < 256) lcnt[t] = 0;
    __syncthreads();
    int i = lo + t;
    for (; i + 3 * 512 < hi; i += 4 * 512) {
        int v0 = binned[i], v1 = binned[i + 512];
        int v2 = binned[i + 1024], v3 = binned[i + 1536];
        atomicAdd(&lcnt[v0 & 255], 1);
        atomicAdd(&lcnt[v1 & 255], 1);
        atomicAdd(&lcnt[v2 & 255], 1);
        atomicAdd(&lcnt[v3 & 255], 1);
    }
    for (; i < hi; i += 512) atomicAdd(&lcnt[binned[i] & 255], 1);
    __syncthreads();
    int c = 0;
    if (t < 256) { c = lcnt[t]; sc[t] = c; }
    __syncthreads();
    for (int off = 1; off < 256; off <<= 1) {
        int u = 0;
        if (t < 256 && t >= off) u = sc[t - off];
        __syncthreads();
        if (t < 256) sc[t] += u;
        __syncthreads();
    }
    if (t < 256) {
        int excl = sc[t] - c;
        const int node = (b << BKT_SHIFT) + t;
        if (node < n) {
            row_start[node] = lo + excl;
            cnt[node] = c;
            dinv[node] = rsqrtf((float)c + 1.0f);
        }
        lcnt[t] = excl;  // becomes the local cursor
    }
    __syncthreads();
    i = lo + t;
    for (; i + 3 * 512 < hi; i += 4 * 512) {
        int v0 = binned[i], v1 = binned[i + 512];
        int v2 = binned[i + 1024], v3 = binned[i + 1536];
        int r0 = atomicAdd(&lcnt[v0 & 255], 1); csr[lo + r0] = v0 >> BKT_SHIFT;
        int r1 = atomicAdd(&lcnt[v1 & 255], 1); csr[lo + r1] = v1 >> BKT_SHIFT;
        int r2 = atomicAdd(&lcnt[v2 & 255], 1); csr[lo + r2] = v2 >> BKT_SHIFT;
        int r3 = atomicAdd(&lcnt[v3 & 255], 1); csr[lo + r3] = v3 >> BKT_SHIFT;
    }
    for (; i < hi; i += 512) {
        int v = binned[i];
        int r = atomicAdd(&lcnt[v & 255], 1);
        csr[lo + r] = v >> BKT_SHIFT;
    }
}

// g1[row][o] = (x[row] @ W1)[o] * dinv[row]
// W1 staged in LDS, o-major with XOR swizzle: element (k,o) at word
// o*512 + (k ^ ((o&7)<<2)); lane l reads float4 at o*512 + 4*(l^(o&7))
// (+256 for second k-half) -- conflict-free. 4 rows per wave per iteration.
// launch_bounds(256,4): VGPR<=128 -> 16 waves/CU (4 blocks x 32KB LDS).
#define G1R 4
__global__ __launch_bounds__(256, 4) void k_gemm1(
    const float* __restrict__ x, const float* __restrict__ W1,
    const float* __restrict__ dinv, float* __restrict__ g1, int n) {
    __shared__ float wlds[16 * 512];
    const int t = threadIdx.x;
    for (int i = t; i < 8192; i += 256) {
        int k = i >> 4, o = i & 15;
        wlds[o * 512 + (k ^ ((o & 7) << 2))] = W1[i];
    }
    __syncthreads();

    const int lane = t & 63;
    const int wid  = blockIdx.x * 4 + (t >> 6);
    const int nw   = gridDim.x * 4;
    const float4* __restrict__ xv = (const float4*)x;

    for (int r0 = wid * G1R; r0 < n; r0 += nw * G1R) {
        float4 a[G1R], b[G1R];
#pragma unroll
        for (int r = 0; r < G1R; ++r) {
            a[r] = make_float4(0.f, 0.f, 0.f, 0.f);
            b[r] = a[r];
            if (r0 + r < n) {
                a[r] = xv[(size_t)(r0 + r) * 128 + lane];
                b[r] = xv[(size_t)(r0 + r) * 128 + 64 + lane];
            }
        }
        float acc[G1R][16];
#pragma unroll
        for (int r = 0; r < G1R; ++r)
#pragma unroll
            for (int o = 0; o < 16; ++o) acc[r][o] = 0.f;

#pragma unroll
        for (int o = 0; o < 16; ++o) {
            const int lp = lane ^ (o & 7);
            float4 wa = *(const float4*)&wlds[o * 512 + 4 * lp];
            float4 wb = *(const float4*)&wlds[o * 512 + 256 + 4 * lp];
#pragma unroll
            for (int r = 0; r < G1R; ++r) {
                float s = fmaf(a[r].x, wa.x, acc[r][o]);
                s = fmaf(a[r].y, wa.y, s);
                s = fmaf(a[r].z, wa.z, s);
                s = fmaf(a[r].w, wa.w, s);
                s = fmaf(b[r].x, wb.x, s);
                s = fmaf(b[r].y, wb.y, s);
                s = fmaf(b[r].z, wb.z, s);
                acc[r][o] = fmaf(b[r].w, wb.w, s);
            }
        }
        // Reduce in place (lane permutation lp is reduction-invariant: the
        // sum spans all 64 lanes per output o).
#pragma unroll
        for (int r = 0; r < G1R; ++r) {
            if (r0 + r >= n) break;
#pragma unroll
            for (int i = 0; i < 8; ++i) {
                float send = (lane & 32) ? acc[r][i] : acc[r][i + 8];
                float recv = __shfl_xor(send, 32);
                float keep = (lane & 32) ? acc[r][i + 8] : acc[r][i];
                acc[r][i] = keep + recv;
            }
#pragma unroll
            for (int i = 0; i < 4; ++i) {
                float send = (lane & 16) ? acc[r][i] : acc[r][i + 4];
                float recv = __shfl_xor(send, 16);
                float keep = (lane & 16) ? acc[r][i + 4] : acc[r][i];
                acc[r][i] = keep + recv;
            }
#pragma unroll
            for (int i = 0; i < 2; ++i) {
                float send = (lane & 8) ? acc[r][i] : acc[r][i + 2];
                float recv = __shfl_xor(send, 8);
                float keep = (lane & 8) ? acc[r][i + 2] : acc[r][i];
                acc[r][i] = keep + recv;
            }
            {
                float send = (lane & 4) ? acc[r][0] : acc[r][1];
                float recv = __shfl_xor(send, 4);
                float keep = (lane & 4) ? acc[r][1] : acc[r][0];
                acc[r][0] = keep + recv;
            }
            float v = acc[r][0];
            v += __shfl_xor(v, 1);
            v += __shfl_xor(v, 2);
            if ((lane & 3) == 0)
                g1[(size_t)(r0 + r) * 16 + (lane >> 2)] = v * dinv[r0 + r];
        }
    }
}

// Wave per node: gather-sum g1 over CSR neighbors (4-way MLP unroll), fuse
// h2=relu(...), h3=h2@W2, g2=h3*dinv.
// Lane layout: lane = eo*16 + f (4 edge slots x 16 features).
__global__ __launch_bounds__(256) void k_gather1(
    const int* __restrict__ row_start, const int* __restrict__ cnt,
    const int* __restrict__ csr, const float* __restrict__ g1,
    const float* __restrict__ dinv, const float* __restrict__ W2,
    const float* __restrict__ b1, float* __restrict__ g2, int n) {
    const int wid = blockIdx.x * 4 + (threadIdx.x >> 6);
    if (wid >= n) return;
    const int lane = threadIdx.x & 63;
    const int f = lane & 15, eo = lane >> 4;
    const int base = row_start[wid];
    const int deg = cnt[wid];
    float acc = 0.f;
    int j = eo;
    // 4-way: 4 independent csr+gather chains in flight per lane.
    for (; j + 12 < deg; j += 16) {
        int s0 = csr[base + j];
        int s1 = csr[base + j + 4];
        int s2 = csr[base + j + 8];
        int s3 = csr[base + j + 12];
        float v0 = g1[(size_t)s0 * 16 + f];
        float v1 = g1[(size_t)s1 * 16 + f];
        float v2 = g1[(size_t)s2 * 16 + f];
        float v3 = g1[(size_t)s3 * 16 + f];
        acc += (v0 + v1) + (v2 + v3);
    }
    for (; j < deg; j += 4) {
        int s = csr[base + j];
        acc += g1[(size_t)s * 16 + f];
    }
    acc += __shfl_xor(acc, 16);
    acc += __shfl_xor(acc, 32);
    const float dv = dinv[wid];
    float h2 = fmaxf(fmaf(dv, acc + g1[(size_t)wid * 16 + f], b1[f]), 0.f);
    float p0 = h2 * W2[2 * f], p1 = h2 * W2[2 * f + 1];
#pragma unroll
    for (int m = 1; m < 16; m <<= 1) {
        p0 += __shfl_xor(p0, m);
        p1 += __shfl_xor(p1, m);
    }
    if (lane == 0) ((float2*)g2)[wid] = make_float2(p0 * dv, p1 * dv);
}

// Wave per node: gather-sum float2 g2 over CSR neighbors, fuse bias -> out.
__global__ __launch_bounds__(256) void k_gather2(
    const int* __restrict__ row_start, const int* __restrict__ cnt,
    const int* __restrict__ csr, const float* __restrict__ g2,
    const float* __restrict__ dinv, const float* __restrict__ b2,
    float* __restrict__ out, int n) {
    const int wid = blockIdx.x * 4 + (threadIdx.x >> 6);
    if (wid >= n) return;
    const int lane = threadIdx.x & 63;
    const int base = row_start[wid];
    const int deg = cnt[wid];
    float a0 = 0.f, a1 = 0.f;
    for (int j = lane; j < deg; j += 64) {
        int s = csr[base + j];
        float2 v = ((const float2*)g2)[s];
        a0 += v.x; a1 += v.y;
    }
#pragma unroll
    for (int m = 1; m < 64; m <<= 1) {
        a0 += __shfl_xor(a0, m);
        a1 += __shfl_xor(a1, m);
    }
    if (lane == 0) {
        float dv = dinv[wid];
        float2 g = ((const float2*)g2)[wid];
        ((float2*)out)[wid] = make_float2(fmaf(dv, a0 + g.x, b2[0]),
                                          fmaf(dv, a1 + g.y, b2[1]));
    }
}

extern "C" void kernel_launch(void* const* d_in, const int* in_sizes, int n_in,
                              void* d_out, int out_size, void* d_ws, size_t ws_size,
                              hipStream_t stream) {
    const float* x  = (const float*)d_in[0];
    const int*   ei = (const int*)d_in[1];
    const float* W1 = (const float*)d_in[2];
    const float* b1 = (const float*)d_in[3];
    const float* W2 = (const float*)d_in[4];
    const float* b2 = (const float*)d_in[5];
    float* out = (float*)d_out;

    const int n = in_sizes[0] / 512;
    const int E = in_sizes[1] / 2;
    const int* src = ei;
    const int* dst = ei + E;

    const int NB = (n + (1 << BKT_SHIFT) - 1) >> BKT_SHIFT;      // buckets (<=512)
    const int nb_bin = (E + 256 * BIN_EPT - 1) / (256 * BIN_EPT); // bin blocks

    char* ws = (char*)d_ws;
    size_t off = 0;
    auto alloc = [&](size_t bytes) {
        char* p = ws + off;
        off += (bytes + 255) & ~(size_t)255;
        return p;
    };
    float* dinv      = (float*)alloc((size_t)n * 4);
    float* g1        = (float*)alloc((size_t)n * 16 * 4);
    float* g2        = (float*)alloc((size_t)n * 2 * 4);
    int*   row_start = (int*)alloc((size_t)n * 4);
    int*   cnt       = (int*)alloc((size_t)n * 4);
    int*   csr       = (int*)alloc((size_t)NB * CAP * 4);
    int*   binned    = (int*)alloc((size_t)NB * CAP * 4);
    int*   bucket_cursor = (int*)alloc((size_t)NB * 4);

    hipMemsetAsync(bucket_cursor, 0, (size_t)NB * 4, stream);

    const int nb_w = (n + 3) / 4;    // wave-per-node kernels, 4 waves/block

    // k_bin dynamic LDS: h/ls/gb (3*NB ints) + sorted (4096 ints) + bkt (4096 u16)
    const int bin_lds = 3 * NB * 4 + 256 * BIN_EPT * 4 + 256 * BIN_EPT * 2;

    k_bin<<<nb_bin, 256, bin_lds, stream>>>(src, dst, bucket_cursor, binned, E, NB);
    k_place<<<NB, 512, 0, stream>>>(binned, bucket_cursor, row_start, cnt, dinv, csr, n, NB);
    k_gemm1<<<1024, 256, 0, stream>>>(x, W1, dinv, g1, n);
    k_gather1<<<nb_w, 256, 0, stream>>>(row_start, cnt, csr, g1, dinv, W2, b1, g2, n);
    k_gather2<<<nb_w, 256, 0, stream>>>(row_start, cnt, csr, g2, dinv, b2, out, n);
}

// Round 15
// 205.262 us; speedup vs baseline: 2.0347x; 2.0347x over previous
//
#include <hip/hip_runtime.h>

// GCN 2-layer forward, CSR-gather formulation. All fp32.
// out[d] = dinv[d] * ( sum_{e: src->d} g[src] + g[d] ) + bias,
// where g[i] = (h W)[i] * dinv[i]; self-loop is the +g[d] term.
// CSR built via SINGLE-PASS capacity binning (each dst-bucket owns a fixed
// CAP-slot region; uniform-random dst -> max bucket load ~8200 << CAP=10240):
//   k_bin:    stage edges in regs, LDS hist+scan, one global reserve per
//             (block,bucket) from zero-seeded cursor, LDS counting sort,
//             COALESCED write of packed (src<<8|dst&255) runs into b*CAP+...
//   k_place:  per-bucket (512 thr): per-node counts/scan in LDS, emit
//             row_start (capacity-absolute), cnt, dinv; place csr.
//   k_gemm1:  g1 = (x @ W1) * dinv. W1 in LDS (o-major XOR-swizzled);
//             4 rows/wave/iter with DOUBLE-BUFFERED x prefetch.
//             launch_bounds(256,2): ~150 VGPR live, no spill. ((256,4)
//             capped VGPR at 64 -> scratch spills, FETCH 102->879MB,
//             gemm1 284us -- r14 post-mortem.)
//   k_gather1: CSR gather of g1 (4-way MLP unroll) + fused relu/W2 -> g2
//   k_gather2: CSR gather of g2 + bias -> out

#define BKT_SHIFT 8            // 256 nodes per bucket
#define BIN_EPT 16             // edges per thread in k_bin (4096/block)
#define CAP 10240              // per-bucket capacity (expected 8184, sigma~90)

// Bin packed edges (src<<8 | dst&255) into per-bucket capacity regions.
// LDS counting sort inside the block -> coalesced run writes.
// Dynamic LDS: h[NB], ls[NB], gb[NB], sorted[4096] int, bkt[4096] ushort.
__global__ __launch_bounds__(256) void k_bin(
    const int* __restrict__ src, const int* __restrict__ dst,
    int* __restrict__ bucket_cursor, int* __restrict__ binned, int E, int NB) {
    extern __shared__ int lds[];
    int* h  = lds;
    int* ls = lds + NB;
    int* gb = lds + 2 * NB;
    int* sorted = lds + 3 * NB;
    unsigned short* bkt = (unsigned short*)(sorted + 256 * BIN_EPT);
    const int t = threadIdx.x;
    const int base = blockIdx.x * (256 * BIN_EPT);
    const int count = min(256 * BIN_EPT, E - base);  // valid edges this block

    for (int b = t; b < NB; b += 256) h[b] = 0;
    __syncthreads();
    // Stage edges in registers + local histogram.
    int s_[BIN_EPT], d_[BIN_EPT];
#pragma unroll
    for (int j = 0; j < BIN_EPT; ++j) {
        int e = base + j * 256 + t;
        if (e < E) {
            s_[j] = src[e];
            d_[j] = dst[e];
            atomicAdd(&h[d_[j] >> BKT_SHIFT], 1);
        }
    }
    __syncthreads();
    // Inclusive Hillis-Steele scan of h into ls (512 padded slots, 2/thread).
    {
        int i0 = t, i1 = t + 256;
        ls[i0] = (i0 < NB) ? h[i0] : 0;
        ls[i1] = (i1 < NB) ? h[i1] : 0;
        __syncthreads();
        for (int off = 1; off < 512; off <<= 1) {
            int a0 = (i0 >= off) ? ls[i0 - off] : 0;
            int a1 = (i1 >= off) ? ls[i1 - off] : 0;
            __syncthreads();
            ls[i0] += a0; ls[i1] += a1;
            __syncthreads();
        }
    }
    // ls -> exclusive; reserve capacity-region space; h becomes sort cursor.
    for (int b = t; b < NB; b += 256) {
        int c = h[b];
        int ex = ls[b] - c;
        ls[b] = ex;
        gb[b] = (c > 0) ? (b * CAP + atomicAdd(&bucket_cursor[b], c)) : 0;
        h[b] = ex;
    }
    __syncthreads();
    // Counting sort into LDS.
#pragma unroll
    for (int j = 0; j < BIN_EPT; ++j) {
        int e = base + j * 256 + t;
        if (e < E) {
            int b = d_[j] >> BKT_SHIFT;
            int r = atomicAdd(&h[b], 1);
            sorted[r] = (s_[j] << BKT_SHIFT) | (d_[j] & 255);
            bkt[r] = (unsigned short)b;
        }
    }
    __syncthreads();
    // Coalesced write-out: consecutive slots -> consecutive positions in the
    // same bucket's reserved run.
#pragma unroll
    for (int j = 0; j < BIN_EPT; ++j) {
        int i = j * 256 + t;
        if (i < count) {
            int b = bkt[i];
            binned[gb[b] + (i - ls[b])] = sorted[i];
        }
    }
}

// One block (512 thr) per bucket: per-node degree count in LDS (4x staged),
// LDS scan -> row_start (capacity-absolute) + cnt + dinv, place csr.
__global__ __launch_bounds__(512) void k_place(
    const int* __restrict__ binned, const int* __restrict__ bucket_cursor,
    int* __restrict__ row_start, int* __restrict__ cnt, float* __restrict__ dinv,
    int* __restrict__ csr, int n, int NB) {
    __shared__ int lcnt[256], sc[256];
    const int b = blockIdx.x;
    const int t = threadIdx.x;
    const int lo = b * CAP;
    const int hi = lo + bucket_cursor[b];  // final cursor == bucket count
    if (t < 256) lcnt[t] = 0;
    __syncthreads();
    int i = lo + t;
    for (; i + 3 * 512 < hi; i += 4 * 512) {
        int v0 = binned[i], v1 = binned[i + 512];
        int v2 = binned[i + 1024], v3 = binned[i + 1536];
        atomicAdd(&lcnt[v0 & 255], 1);
        atomicAdd(&lcnt[v1 & 255], 1);
        atomicAdd(&lcnt[v2 & 255], 1);
        atomicAdd(&lcnt[v3 & 255], 1);
    }
    for (; i < hi; i += 512) atomicAdd(&lcnt[binned[i] & 255], 1);
    __syncthreads();
    int c = 0;
    if (t < 256) { c = lcnt[t]; sc[t] = c; }
    __syncthreads();
    for (int off = 1; off < 256; off <<= 1) {
        int u = 0;
        if (t < 256 && t >= off) u = sc[t - off];
        __syncthreads();
        if (t < 256) sc[t] += u;
        __syncthreads();
    }
    if (t < 256) {
        int excl = sc[t] - c;
        const int node = (b << BKT_SHIFT) + t;
        if (node < n) {
            row_start[node] = lo + excl;
            cnt[node] = c;
            dinv[node] = rsqrtf((float)c + 1.0f);
        }
        lcnt[t] = excl;  // becomes the local cursor
    }
    __syncthreads();
    i = lo + t;
    for (; i + 3 * 512 < hi; i += 4 * 512) {
        int v0 = binned[i], v1 = binned[i + 512];
        int v2 = binned[i + 1024], v3 = binned[i + 1536];
        int r0 = atomicAdd(&lcnt[v0 & 255], 1); csr[lo + r0] = v0 >> BKT_SHIFT;
        int r1 = atomicAdd(&lcnt[v1 & 255], 1); csr[lo + r1] = v1 >> BKT_SHIFT;
        int r2 = atomicAdd(&lcnt[v2 & 255], 1); csr[lo + r2] = v2 >> BKT_SHIFT;
        int r3 = atomicAdd(&lcnt[v3 & 255], 1); csr[lo + r3] = v3 >> BKT_SHIFT;
    }
    for (; i < hi; i += 512) {
        int v = binned[i];
        int r = atomicAdd(&lcnt[v & 255], 1);
        csr[lo + r] = v >> BKT_SHIFT;
    }
}

// g1[row][o] = (x[row] @ W1)[o] * dinv[row]
// W1 staged in LDS, o-major with XOR swizzle: element (k,o) at word
// o*512 + (k ^ ((o&7)<<2)); lane l reads float4 at o*512 + 4*(l^(o&7))
// (+256 for second k-half) -- conflict-free. 4 rows per wave per iteration,
// DOUBLE-BUFFERED x prefetch (load iter i+1's rows before iter i's FMAs).
// launch_bounds(256,2): ~150 VGPR live (acc 64 + x 64 + W slice) -> no spill.
#define G1R 4
__global__ __launch_bounds__(256, 2) void k_gemm1(
    const float* __restrict__ x, const float* __restrict__ W1,
    const float* __restrict__ dinv, float* __restrict__ g1, int n) {
    __shared__ float wlds[16 * 512];
    const int t = threadIdx.x;
    for (int i = t; i < 8192; i += 256) {
        int k = i >> 4, o = i & 15;
        wlds[o * 512 + (k ^ ((o & 7) << 2))] = W1[i];
    }
    __syncthreads();

    const int lane = t & 63;
    const int wid  = blockIdx.x * 4 + (t >> 6);
    const int nw   = gridDim.x * 4;
    const float4* __restrict__ xv = (const float4*)x;

    int r0 = wid * G1R;
    float4 a[G1R], b[G1R];
#pragma unroll
    for (int r = 0; r < G1R; ++r) {
        a[r] = make_float4(0.f, 0.f, 0.f, 0.f);
        b[r] = a[r];
        if (r0 + r < n) {
            a[r] = xv[(size_t)(r0 + r) * 128 + lane];
            b[r] = xv[(size_t)(r0 + r) * 128 + 64 + lane];
        }
    }

    while (r0 < n) {
        const int r1 = r0 + nw * G1R;
        // Prefetch next iteration's rows (overlaps with FMAs below).
        float4 a2[G1R], b2[G1R];
#pragma unroll
        for (int r = 0; r < G1R; ++r) {
            a2[r] = make_float4(0.f, 0.f, 0.f, 0.f);
            b2[r] = a2[r];
            if (r1 + r < n) {
                a2[r] = xv[(size_t)(r1 + r) * 128 + lane];
                b2[r] = xv[(size_t)(r1 + r) * 128 + 64 + lane];
            }
        }

        float acc[G1R][16];
#pragma unroll
        for (int r = 0; r < G1R; ++r)
#pragma unroll
            for (int o = 0; o < 16; ++o) acc[r][o] = 0.f;

#pragma unroll
        for (int o = 0; o < 16; ++o) {
            const int lp = lane ^ (o & 7);
            float4 wa = *(const float4*)&wlds[o * 512 + 4 * lp];
            float4 wb = *(const float4*)&wlds[o * 512 + 256 + 4 * lp];
#pragma unroll
            for (int r = 0; r < G1R; ++r) {
                float s = fmaf(a[r].x, wa.x, acc[r][o]);
                s = fmaf(a[r].y, wa.y, s);
                s = fmaf(a[r].z, wa.z, s);
                s = fmaf(a[r].w, wa.w, s);
                s = fmaf(b[r].x, wb.x, s);
                s = fmaf(b[r].y, wb.y, s);
                s = fmaf(b[r].z, wb.z, s);
                acc[r][o] = fmaf(b[r].w, wb.w, s);
            }
        }
        // Reduce in place (lane permutation lp is reduction-invariant: the
        // sum spans all 64 lanes per output o).
#pragma unroll
        for (int r = 0; r < G1R; ++r) {
            if (r0 + r >= n) break;
#pragma unroll
            for (int i = 0; i < 8; ++i) {
                float send = (lane & 32) ? acc[r][i] : acc[r][i + 8];
                float recv = __shfl_xor(send, 32);
                float keep = (lane & 32) ? acc[r][i + 8] : acc[r][i];
                acc[r][i] = keep + recv;
            }
#pragma unroll
            for (int i = 0; i < 4; ++i) {
                float send = (lane & 16) ? acc[r][i] : acc[r][i + 4];
                float recv = __shfl_xor(send, 16);
                float keep = (lane & 16) ? acc[r][i + 4] : acc[r][i];
                acc[r][i] = keep + recv;
            }
#pragma unroll
            for (int i = 0; i < 2; ++i) {
                float send = (lane & 8) ? acc[r][i] : acc[r][i + 2];
                float recv = __shfl_xor(send, 8);
                float keep = (lane & 8) ? acc[r][i + 2] : acc[r][i];
                acc[r][i] = keep + recv;
            }
            {
                float send = (lane & 4) ? acc[r][0] : acc[r][1];
                float recv = __shfl_xor(send, 4);
                float keep = (lane & 4) ? acc[r][1] : acc[r][0];
                acc[r][0] = keep + recv;
            }
            float v = acc[r][0];
            v += __shfl_xor(v, 1);
            v += __shfl_xor(v, 2);
            if ((lane & 3) == 0)
                g1[(size_t)(r0 + r) * 16 + (lane >> 2)] = v * dinv[r0 + r];
        }
        r0 = r1;
#pragma unroll
        for (int r = 0; r < G1R; ++r) { a[r] = a2[r]; b[r] = b2[r]; }
    }
}

// Wave per node: gather-sum g1 over CSR neighbors (4-way MLP unroll), fuse
// h2=relu(...), h3=h2@W2, g2=h3*dinv.
// Lane layout: lane = eo*16 + f (4 edge slots x 16 features).
__global__ __launch_bounds__(256) void k_gather1(
    const int* __restrict__ row_start, const int* __restrict__ cnt,
    const int* __restrict__ csr, const float* __restrict__ g1,
    const float* __restrict__ dinv, const float* __restrict__ W2,
    const float* __restrict__ b1, float* __restrict__ g2, int n) {
    const int wid = blockIdx.x * 4 + (threadIdx.x >> 6);
    if (wid >= n) return;
    const int lane = threadIdx.x & 63;
    const int f = lane & 15, eo = lane >> 4;
    const int base = row_start[wid];
    const int deg = cnt[wid];
    float acc = 0.f;
    int j = eo;
    // 4-way: 4 independent csr+gather chains in flight per lane.
    for (; j + 12 < deg; j += 16) {
        int s0 = csr[base + j];
        int s1 = csr[base + j + 4];
        int s2 = csr[base + j + 8];
        int s3 = csr[base + j + 12];
        float v0 = g1[(size_t)s0 * 16 + f];
        float v1 = g1[(size_t)s1 * 16 + f];
        float v2 = g1[(size_t)s2 * 16 + f];
        float v3 = g1[(size_t)s3 * 16 + f];
        acc += (v0 + v1) + (v2 + v3);
    }
    for (; j < deg; j += 4) {
        int s = csr[base + j];
        acc += g1[(size_t)s * 16 + f];
    }
    acc += __shfl_xor(acc, 16);
    acc += __shfl_xor(acc, 32);
    const float dv = dinv[wid];
    float h2 = fmaxf(fmaf(dv, acc + g1[(size_t)wid * 16 + f], b1[f]), 0.f);
    float p0 = h2 * W2[2 * f], p1 = h2 * W2[2 * f + 1];
#pragma unroll
    for (int m = 1; m < 16; m <<= 1) {
        p0 += __shfl_xor(p0, m);
        p1 += __shfl_xor(p1, m);
    }
    if (lane == 0) ((float2*)g2)[wid] = make_float2(p0 * dv, p1 * dv);
}

// Wave per node: gather-sum float2 g2 over CSR neighbors, fuse bias -> out.
__global__ __launch_bounds__(256) void k_gather2(
    const int* __restrict__ row_start, const int* __restrict__ cnt,
    const int* __restrict__ csr, const float* __restrict__ g2,
    const float* __restrict__ dinv, const float* __restrict__ b2,
    float* __restrict__ out, int n) {
    const int wid = blockIdx.x * 4 + (threadIdx.x >> 6);
    if (wid >= n) return;
    const int lane = threadIdx.x & 63;
    const int base = row_start[wid];
    const int deg = cnt[wid];
    float a0 = 0.f, a1 = 0.f;
    for (int j = lane; j < deg; j += 64) {
        int s = csr[base + j];
        float2 v = ((const float2*)g2)[s];
        a0 += v.x; a1 += v.y;
    }
#pragma unroll
    for (int m = 1; m < 64; m <<= 1) {
        a0 += __shfl_xor(a0, m);
        a1 += __shfl_xor(a1, m);
    }
    if (lane == 0) {
        float dv = dinv[wid];
        float2 g = ((const float2*)g2)[wid];
        ((float2*)out)[wid] = make_float2(fmaf(dv, a0 + g.x, b2[0]),
                                          fmaf(dv, a1 + g.y, b2[1]));
    }
}

extern "C" void kernel_launch(void* const* d_in, const int* in_sizes, int n_in,
                              void* d_out, int out_size, void* d_ws, size_t ws_size,
                              hipStream_t stream) {
    const float* x  = (const float*)d_in[0];
    const int*   ei = (const int*)d_in[1];
    const float* W1 = (const float*)d_in[2];
    const float* b1 = (const float*)d_in[3];
    const float* W2 = (const float*)d_in[4];
    const float* b2 = (const float*)d_in[5];
    float* out = (float*)d_out;

    const int n = in_sizes[0] / 512;
    const int E = in_sizes[1] / 2;
    const int* src = ei;
    const int* dst = ei + E;

    const int NB = (n + (1 << BKT_SHIFT) - 1) >> BKT_SHIFT;      // buckets (<=512)
    const int nb_bin = (E + 256 * BIN_EPT - 1) / (256 * BIN_EPT); // bin blocks

    char* ws = (char*)d_ws;
    size_t off = 0;
    auto alloc = [&](size_t bytes) {
        char* p = ws + off;
        off += (bytes + 255) & ~(size_t)255;
        return p;
    };
    float* dinv      = (float*)alloc((size_t)n * 4);
    float* g1        = (float*)alloc((size_t)n * 16 * 4);
    float* g2        = (float*)alloc((size_t)n * 2 * 4);
    int*   row_start = (int*)alloc((size_t)n * 4);
    int*   cnt       = (int*)alloc((size_t)n * 4);
    int*   csr       = (int*)alloc((size_t)NB * CAP * 4);
    int*   binned    = (int*)alloc((size_t)NB * CAP * 4);
    int*   bucket_cursor = (int*)alloc((size_t)NB * 4);

    hipMemsetAsync(bucket_cursor, 0, (size_t)NB * 4, stream);

    const int nb_w = (n + 3) / 4;    // wave-per-node kernels, 4 waves/block

    // k_bin dynamic LDS: h/ls/gb (3*NB ints) + sorted (4096 ints) + bkt (4096 u16)
    const int bin_lds = 3 * NB * 4 + 256 * BIN_EPT * 4 + 256 * BIN_EPT * 2;

    k_bin<<<nb_bin, 256, bin_lds, stream>>>(src, dst, bucket_cursor, binned, E, NB);
    k_place<<<NB, 512, 0, stream>>>(binned, bucket_cursor, row_start, cnt, dinv, csr, n, NB);
    k_gemm1<<<1024, 256, 0, stream>>>(x, W1, dinv, g1, n);
    k_gather1<<<nb_w, 256, 0, stream>>>(row_start, cnt, csr, g1, dinv, W2, b1, g2, n);
    k_gather2<<<nb_w, 256, 0, stream>>>(row_start, cnt, csr, g2, dinv, b2, out, n);
}